// Round 9
// baseline (191.503 us; speedup 1.0000x reference)
//
#include <hip/hip_runtime.h>

#define HIDDEN   2048
#define GROWS    6144            // 3 * HIDDEN
#define VOCAB    53
#define LAYERS   6
#define NBLK     512             // 2 blocks/CU -> all co-resident
#define NT       512             // 8 waves: 4 hh-producer + 4 ih-consumer
#define SLOTS    4               // j's per block; j = bid + NBLK*slot
#define SUB_LINES   32
#define BLK_PER_SUB (NBLK / SUB_LINES)   // 16

// ws layout (bytes):
//   [0, 49152)       float h_work[6][2048]   (relaxed bypass atomics only)
//   [49152, 61440)   per layer: 32 sub-counters, 64B apart
#define WS_H_OFF     0
#define WS_SUB_OFF   49152
#define WS_CTR_BYTES (SUB_LINES * 64 * LAYERS)

typedef unsigned long long ull;
#define VMCNT0 asm volatile("s_waitcnt vmcnt(0)" ::: "memory")
union FU { ull u; float2 f; };

__device__ __forceinline__ float dot4(float4 a, float4 b) {
    return a.x * b.x + a.y * b.y + a.z * b.z + a.w * b.w;
}

// Persistent fused GRU stack, wave-specialized:
//   waves 0-3 (producers): gh[l][g][slot] = w_hh row · hidden[l] for ALL 6
//     layers, no polls/barriers -> continuous HBM stream that fills every
//     cross-block barrier gap. Results to LDS, workgroup-release counter.
//   waves 4-7 (consumers): per layer: poll sub-counters (wave 4 only, LDS
//     flag relay) -> bypass-load x -> stream 3 w_ih rows (post-poll by
//     design: nothing for the compiler to sink) -> gates -> publish h via
//     relaxed bypass store + vmcnt(0) + hierarchical sub-counter bump.
// No agent-scope fences anywhere (they wb/inv whole L2 on gfx950).
__global__ __launch_bounds__(NT, 4) void gru_fused(
    const int*   __restrict__ token,
    const float* __restrict__ hidden,   // [6][2048]
    const float* __restrict__ emb,      // [53][2048]
    const float* __restrict__ w_ih,     // [6][6144][2048]
    const float* __restrict__ w_hh,     // [6][6144][2048]
    const float* __restrict__ b_ih,     // [6][6144]
    const float* __restrict__ b_hh,     // [6][6144]
    const float* __restrict__ w_dec,    // [53][2048]
    const float* __restrict__ b_dec,    // [53]
    float*       __restrict__ out,      // [53 logits][6*2048 h_new]
    char*        __restrict__ ws)
{
    const int bid  = blockIdx.x;
    const int tid  = threadIdx.x;
    const int wave = tid >> 6;
    const int lane = tid & 63;

    float*    h_work = (float*)(ws + WS_H_OFF);
    unsigned* subc   = (unsigned*)(ws + WS_SUB_OFF);

    __shared__ float    ghbuf[LAYERS][3][SLOTS];
    __shared__ unsigned ghcnt[LAYERS];    // producer waves done (-> 4)
    __shared__ unsigned ihdone[LAYERS];   // consumer waves done (-> 4)
    __shared__ unsigned lready[LAYERS];   // poll relay flag
    if (tid < LAYERS) { ghcnt[tid] = 0; ihdone[tid] = 0; lready[tid] = 0; }
    __syncthreads();

    if (wave < 4) {
        // ================= producer: w_hh stream, all layers =================
        const int slot = wave;
        const int j    = bid + NBLK * slot;
        for (int l = 0; l < LAYERS; ++l) {
            const float* Whh = w_hh + (size_t)l * GROWS * HIDDEN;
            float4 hv[8];
            {
                const float4* hs = (const float4*)(hidden + (size_t)l * HIDDEN);
                #pragma unroll
                for (int u = 0; u < 8; ++u) hv[u] = hs[u * 64 + lane];
            }
            const float4* W0 = (const float4*)(Whh + ((size_t)0 * HIDDEN + j) * HIDDEN);
            const float4* W1 = (const float4*)(Whh + ((size_t)1 * HIDDEN + j) * HIDDEN);
            const float4* W2 = (const float4*)(Whh + ((size_t)2 * HIDDEN + j) * HIDDEN);
            float a0 = 0.f, a1 = 0.f, a2 = 0.f;
            #pragma unroll
            for (int u = 0; u < 8; ++u) {
                a0 += dot4(W0[u * 64 + lane], hv[u]);
                a1 += dot4(W1[u * 64 + lane], hv[u]);
                a2 += dot4(W2[u * 64 + lane], hv[u]);
            }
            #pragma unroll
            for (int o = 32; o; o >>= 1) {
                a0 += __shfl_down(a0, o, 64);
                a1 += __shfl_down(a1, o, 64);
                a2 += __shfl_down(a2, o, 64);
            }
            if (lane == 0) {
                ghbuf[l][0][slot] = a0;
                ghbuf[l][1][slot] = a1;
                ghbuf[l][2][slot] = a2;
                __hip_atomic_fetch_add(&ghcnt[l], 1u, __ATOMIC_RELEASE,
                                       __HIP_MEMORY_SCOPE_WORKGROUP);
            }
        }
    } else {
        // ================= consumer: serial w_ih chain =================
        const int slot = wave - 4;
        const int j    = bid + NBLK * slot;
        for (int l = 0; l < LAYERS; ++l) {
            // pre-poll: biases + previous hidden (tiny, off critical path)
            const float* bi = b_ih + (size_t)l * GROWS;
            const float* bh = b_hh + (size_t)l * GROWS;
            const float bir = bi[j], biz = bi[j + HIDDEN], bin = bi[j + 2 * HIDDEN];
            const float bhr = bh[j], bhz = bh[j + HIDDEN], bhn = bh[j + 2 * HIDDEN];
            const float hprev = hidden[(size_t)l * HIDDEN + j];

            if (l > 0) {
                if (wave == 4) {
                    const unsigned* sc = subc + (size_t)(l - 1) * SUB_LINES * 16;
                    for (;;) {
                        unsigned c = BLK_PER_SUB;
                        if (lane < SUB_LINES)
                            c = __hip_atomic_load(&sc[lane * 16], __ATOMIC_RELAXED,
                                                  __HIP_MEMORY_SCOPE_AGENT);
                        if (__all(c >= BLK_PER_SUB)) break;
                        __builtin_amdgcn_s_sleep(1);
                    }
                    __hip_atomic_store(&lready[l], 1u, __ATOMIC_RELEASE,
                                       __HIP_MEMORY_SCOPE_WORKGROUP);
                } else {
                    while (!__hip_atomic_load(&lready[l], __ATOMIC_ACQUIRE,
                                              __HIP_MEMORY_SCOPE_WORKGROUP))
                        __builtin_amdgcn_s_sleep(1);
                }
            }

            // x fragment (bypass atomics for l>0: producer stored bypass)
            float4 xr[8];
            if (l == 0) {
                const float4* xs = (const float4*)(emb + (size_t)token[0] * HIDDEN);
                #pragma unroll
                for (int u = 0; u < 8; ++u) xr[u] = xs[u * 64 + lane];
            } else {
                const ull* hsrc = (const ull*)(h_work + (size_t)(l - 1) * HIDDEN);
                #pragma unroll
                for (int u = 0; u < 8; ++u) {
                    FU A, B;
                    A.u = __hip_atomic_load(&hsrc[(u * 64 + lane) * 2], __ATOMIC_RELAXED,
                                            __HIP_MEMORY_SCOPE_AGENT);
                    B.u = __hip_atomic_load(&hsrc[(u * 64 + lane) * 2 + 1], __ATOMIC_RELAXED,
                                            __HIP_MEMORY_SCOPE_AGENT);
                    xr[u] = make_float4(A.f.x, A.f.y, B.f.x, B.f.y);
                }
            }

            // 3 w_ih row dots (issued post-poll; producers cover the gaps)
            const float* Wih = w_ih + (size_t)l * GROWS * HIDDEN;
            const float4* W0 = (const float4*)(Wih + ((size_t)0 * HIDDEN + j) * HIDDEN);
            const float4* W1 = (const float4*)(Wih + ((size_t)1 * HIDDEN + j) * HIDDEN);
            const float4* W2 = (const float4*)(Wih + ((size_t)2 * HIDDEN + j) * HIDDEN);
            float a0 = 0.f, a1 = 0.f, a2 = 0.f;
            #pragma unroll
            for (int u = 0; u < 8; ++u) {
                a0 += dot4(W0[u * 64 + lane], xr[u]);
                a1 += dot4(W1[u * 64 + lane], xr[u]);
                a2 += dot4(W2[u * 64 + lane], xr[u]);
            }
            #pragma unroll
            for (int o = 32; o; o >>= 1) {
                a0 += __shfl_down(a0, o, 64);
                a1 += __shfl_down(a1, o, 64);
                a2 += __shfl_down(a2, o, 64);
            }

            if (lane == 0) {
                // wait for this block's producers (always progressing)
                while (__hip_atomic_load(&ghcnt[l], __ATOMIC_ACQUIRE,
                                         __HIP_MEMORY_SCOPE_WORKGROUP) < 4u)
                    __builtin_amdgcn_s_sleep(1);
                float ghr = ghbuf[l][0][slot] + bhr;
                float ghz = ghbuf[l][1][slot] + bhz;
                float ghn = ghbuf[l][2][slot] + bhn;
                float gir = a0 + bir, giz = a1 + biz, gin = a2 + bin;
                float r = 1.f / (1.f + __expf(-(gir + ghr)));
                float z = 1.f / (1.f + __expf(-(giz + ghz)));
                float n = tanhf(gin + r * ghn);
                float hv = (1.f - z) * n + z * hprev;
                __hip_atomic_store(&h_work[(size_t)l * HIDDEN + j], hv,
                                   __ATOMIC_RELAXED, __HIP_MEMORY_SCOPE_AGENT);
                out[VOCAB + (size_t)l * HIDDEN + j] = hv;
            }
            VMCNT0;   // h store performed at coherence point before signaling
            if (lane == 0) {
                unsigned old = __hip_atomic_fetch_add(&ihdone[l], 1u, __ATOMIC_ACQ_REL,
                                                      __HIP_MEMORY_SCOPE_WORKGROUP);
                if (old == 3u)   // last consumer wave: cross-block signal
                    __hip_atomic_fetch_add(
                        &subc[((size_t)l * SUB_LINES + (bid & (SUB_LINES - 1))) * 16],
                        1u, __ATOMIC_RELAXED, __HIP_MEMORY_SCOPE_AGENT);
            }
        }
    }

    // ---- decode: logits = w_dec @ h[5] + b_dec (blocks 0..52) ----
    if (bid < VOCAB) {
        if (wave == 0) {
            const unsigned* sc = subc + (size_t)(LAYERS - 1) * SUB_LINES * 16;
            for (;;) {
                unsigned c = BLK_PER_SUB;
                if (lane < SUB_LINES)
                    c = __hip_atomic_load(&sc[lane * 16], __ATOMIC_RELAXED,
                                          __HIP_MEMORY_SCOPE_AGENT);
                if (__all(c >= BLK_PER_SUB)) break;
                __builtin_amdgcn_s_sleep(1);
            }
        }
        __syncthreads();
        // HIDDEN/4 == 512 == NT: one float4 per thread
        float4 a = ((const float4*)(w_dec + (size_t)bid * HIDDEN))[tid];
        const ull* hsrc = (const ull*)(h_work + (size_t)(LAYERS - 1) * HIDDEN);
        FU A, B;
        A.u = __hip_atomic_load(&hsrc[2 * tid], __ATOMIC_RELAXED,
                                __HIP_MEMORY_SCOPE_AGENT);
        B.u = __hip_atomic_load(&hsrc[2 * tid + 1], __ATOMIC_RELAXED,
                                __HIP_MEMORY_SCOPE_AGENT);
        float s = a.x * A.f.x + a.y * A.f.y + a.z * B.f.x + a.w * B.f.y;
        #pragma unroll
        for (int o = 32; o; o >>= 1) s += __shfl_down(s, o, 64);
        __shared__ float dred[8];
        if (lane == 0) dred[wave] = s;
        __syncthreads();
        if (tid == 0) {
            float t = 0.f;
            #pragma unroll
            for (int w = 0; w < 8; ++w) t += dred[w];
            out[bid] = t + b_dec[bid];
        }
    }
}

extern "C" void kernel_launch(void* const* d_in, const int* in_sizes, int n_in,
                              void* d_out, int out_size, void* d_ws, size_t ws_size,
                              hipStream_t stream) {
    const int*   token  = (const int*)  d_in[0];
    const float* hidden = (const float*)d_in[1];
    const float* emb    = (const float*)d_in[2];
    const float* w_ih   = (const float*)d_in[3];
    const float* w_hh   = (const float*)d_in[4];
    const float* b_ih   = (const float*)d_in[5];
    const float* b_hh   = (const float*)d_in[6];
    const float* w_dec  = (const float*)d_in[7];
    const float* b_dec  = (const float*)d_in[8];

    float* out = (float*)d_out;
    char*  ws  = (char*)d_ws;

    // zero the barrier counters (graph replays reuse ws)
    (void)hipMemsetAsync(ws + WS_SUB_OFF, 0, WS_CTR_BYTES, stream);

    gru_fused<<<dim3(NBLK), dim3(NT), 0, stream>>>(
        token, hidden, emb, w_ih, w_hh, b_ih, b_hh,
        w_dec, b_dec, out, ws);
}

// Round 11
// 171.679 us; speedup vs baseline: 1.1155x; 1.1155x over previous
//
#include <hip/hip_runtime.h>

#define HIDDEN   2048
#define GROWS    6144            // 3 * HIDDEN
#define VOCAB    53
#define LAYERS   6
#define NBLK     512             // 2 blocks/CU -> co-residency PROVEN (R6/R8/R9)
#define NWAVE    12
#define NT       768             // 12 waves = 3 gates x 4 j-slots, 1 row/wave/stream
#define JPB      4
#define SUB_LINES   32
#define BLK_PER_SUB (NBLK / SUB_LINES)   // 16

// ws layout (bytes):
//   [0, 49152)       float h_work[6][2048]   (relaxed bypass atomics only)
//   [49152, 61440)   per layer: 32 sub-counters, 64B apart
#define WS_H_OFF     0
#define WS_SUB_OFF   49152
#define WS_CTR_BYTES (SUB_LINES * 64 * LAYERS)

typedef unsigned long long ull;
// memory-clobber pin: all VMEM issued above completes HERE; compiler cannot
// sink those loads below (asm memory barrier), so weight bytes stream
// BEFORE the poll window instead of serializing after it.
#define PIN_VM asm volatile("s_waitcnt vmcnt(0)" ::: "memory")
union FU { ull u; float2 f; };

__device__ __forceinline__ float dot4(float4 a, float4 b) {
    return a.x * b.x + a.y * b.y + a.z * b.z + a.w * b.w;
}

// Persistent fused GRU stack. R6 protocol (relaxed bypass atomics, vmcnt ack,
// hierarchical sub-counters, NO agent fences) + pinned w_ih prefetch.
// Per layer, per wave (gate g = wave>>2, slot = wave&3, j = bid+512*slot):
//   A: gh = w_hh row · hidden[l]                (chain-independent stream)
//   P: w_ih row -> wf[8] registers, then PIN    (streams pre-poll)
//   B: wave 0 ballot-polls 32 sub-counters of layer l-1
//   C: gi = wf · x (x staged in LDS via bypass) (no HBM on critical path)
//   D: wave 0 lane<4 gates -> publish h (bypass store + vmcnt ack) -> signal
__global__ __launch_bounds__(NT, 6) void gru_fused(
    const int*   __restrict__ token,
    const float* __restrict__ hidden,   // [6][2048]
    const float* __restrict__ emb,      // [53][2048]
    const float* __restrict__ w_ih,     // [6][6144][2048]
    const float* __restrict__ w_hh,     // [6][6144][2048]
    const float* __restrict__ b_ih,     // [6][6144]
    const float* __restrict__ b_hh,     // [6][6144]
    const float* __restrict__ w_dec,    // [53][2048]
    const float* __restrict__ b_dec,    // [53]
    float*       __restrict__ out,      // [53 logits][6*2048 h_new]
    char*        __restrict__ ws)
{
    const int bid  = blockIdx.x;
    const int tid  = threadIdx.x;
    const int wave = tid >> 6;
    const int lane = tid & 63;
    const int g    = wave >> 2;              // gate 0..2
    const int slot = wave & 3;               // j-slot 0..3
    const int j    = bid + NBLK * slot;

    float*    h_work = (float*)(ws + WS_H_OFF);
    unsigned* subc   = (unsigned*)(ws + WS_SUB_OFF);

    __shared__ float xlds[HIDDEN];           // 8 KB staged x
    __shared__ float rgh[3][JPB];
    __shared__ float rgi[3][JPB];

    const float* x0 = emb + (size_t)token[0] * HIDDEN;

    for (int l = 0; l < LAYERS; ++l) {
        const size_t lbase = (size_t)l * GROWS * HIDDEN;
        const size_t roff  = ((size_t)g * HIDDEN + (size_t)j) * HIDDEN;

        // ---- phase A: gh = w_hh row · hidden[l] (streams now) ----
        float a = 0.f;
        {
            const float4* W  = (const float4*)(w_hh + lbase + roff);
            const float4* Hs = (const float4*)(hidden + (size_t)l * HIDDEN);
            #pragma unroll
            for (int u = 0; u < 8; ++u)
                a += dot4(W[u * 64 + lane], Hs[u * 64 + lane]);
        }

        // ---- bias/hprev preload (wave 0 lane<4, pre-poll) ----
        float bir = 0.f, biz = 0.f, bin = 0.f, bhr = 0.f, bhz = 0.f, bhn = 0.f,
              hprev = 0.f;
        if (wave == 0 && lane < JPB) {
            const int jj = bid + NBLK * lane;
            const float* bi = b_ih + (size_t)l * GROWS;
            const float* bh = b_hh + (size_t)l * GROWS;
            bir = bi[jj]; biz = bi[jj + HIDDEN]; bin = bi[jj + 2 * HIDDEN];
            bhr = bh[jj]; bhz = bh[jj + HIDDEN]; bhn = bh[jj + 2 * HIDDEN];
            hprev = hidden[(size_t)l * HIDDEN + jj];
        }

        // ---- P: prefetch w_ih row into registers, then PIN ----
        float4 wf[8];
        {
            const float4* Wi = (const float4*)(w_ih + lbase + roff);
            #pragma unroll
            for (int u = 0; u < 8; ++u) wf[u] = Wi[u * 64 + lane];
        }
        PIN_VM;   // weight stream completes before the poll window

        // wave-reduce of A (VALU only)
        #pragma unroll
        for (int o = 32; o; o >>= 1) a += __shfl_down(a, o, 64);

        // ---- phase B: wave 0 ballot-polls layer l-1 sub-counters ----
        if (l > 0 && wave == 0) {
            const unsigned* sc = subc + (size_t)(l - 1) * SUB_LINES * 16;
            for (;;) {
                unsigned c = BLK_PER_SUB;
                if (lane < SUB_LINES)
                    c = __hip_atomic_load(&sc[lane * 16], __ATOMIC_RELAXED,
                                          __HIP_MEMORY_SCOPE_AGENT);
                if (__all(c >= BLK_PER_SUB)) break;
                __builtin_amdgcn_s_sleep(2);
            }
        }
        __syncthreads();

        // ---- stage x into LDS (bypass loads for l>0) ----
        if (l == 0) {
            for (int i = tid; i < HIDDEN / 2; i += NT)
                ((ull*)xlds)[i] = ((const ull*)x0)[i];
        } else {
            const ull* hsrc = (const ull*)(h_work + (size_t)(l - 1) * HIDDEN);
            for (int i = tid; i < HIDDEN / 2; i += NT)
                ((ull*)xlds)[i] = __hip_atomic_load(&hsrc[i], __ATOMIC_RELAXED,
                                                    __HIP_MEMORY_SCOPE_AGENT);
        }
        __syncthreads();

        // ---- phase C: gi = wf · x (LDS reads + VALU only) ----
        float c = 0.f;
        {
            const float4* xl = (const float4*)xlds;
            #pragma unroll
            for (int u = 0; u < 8; ++u) c += dot4(wf[u], xl[u * 64 + lane]);
        }
        #pragma unroll
        for (int o = 32; o; o >>= 1) c += __shfl_down(c, o, 64);

        // ---- funnel ----
        if (lane == 0) { rgh[g][slot] = a; rgi[g][slot] = c; }
        __syncthreads();

        // ---- phase D: wave 0 gates + publish + signal ----
        if (wave == 0) {
            if (lane < JPB) {
                const int jj = bid + NBLK * lane;
                float gir = rgi[0][lane] + bir;
                float giz = rgi[1][lane] + biz;
                float gin = rgi[2][lane] + bin;
                float ghr = rgh[0][lane] + bhr;
                float ghz = rgh[1][lane] + bhz;
                float ghn = rgh[2][lane] + bhn;
                float r = 1.f / (1.f + __expf(-(gir + ghr)));
                float z = 1.f / (1.f + __expf(-(giz + ghz)));
                float n = tanhf(gin + r * ghn);
                float hv = (1.f - z) * n + z * hprev;
                __hip_atomic_store(&h_work[(size_t)l * HIDDEN + jj], hv,
                                   __ATOMIC_RELAXED, __HIP_MEMORY_SCOPE_AGENT);
                out[VOCAB + (size_t)l * HIDDEN + jj] = hv;
            }
            PIN_VM;   // h stores performed at coherence point before signal
            if (lane == 0)
                __hip_atomic_fetch_add(
                    &subc[((size_t)l * SUB_LINES + (bid & (SUB_LINES - 1))) * 16],
                    1u, __ATOMIC_RELAXED, __HIP_MEMORY_SCOPE_AGENT);
        }
        // No trailing barrier: rgh/rgi/xlds are next written only after the
        // next layer's __syncthreads, which wave 0 reaches after phase D.
    }

    // ---- decode: logits = w_dec @ h[5] + b_dec (blocks 0..52) ----
    if (bid < VOCAB) {
        if (wave == 0) {
            const unsigned* sc = subc + (size_t)(LAYERS - 1) * SUB_LINES * 16;
            for (;;) {
                unsigned c = BLK_PER_SUB;
                if (lane < SUB_LINES)
                    c = __hip_atomic_load(&sc[lane * 16], __ATOMIC_RELAXED,
                                          __HIP_MEMORY_SCOPE_AGENT);
                if (__all(c >= BLK_PER_SUB)) break;
                __builtin_amdgcn_s_sleep(2);
            }
        }
        __syncthreads();
        float s = 0.f;
        if (tid < 512) {
            float4 a = ((const float4*)(w_dec + (size_t)bid * HIDDEN))[tid];
            const ull* hsrc = (const ull*)(h_work + (size_t)(LAYERS - 1) * HIDDEN);
            FU A, B;
            A.u = __hip_atomic_load(&hsrc[2 * tid], __ATOMIC_RELAXED,
                                    __HIP_MEMORY_SCOPE_AGENT);
            B.u = __hip_atomic_load(&hsrc[2 * tid + 1], __ATOMIC_RELAXED,
                                    __HIP_MEMORY_SCOPE_AGENT);
            s = a.x * A.f.x + a.y * A.f.y + a.z * B.f.x + a.w * B.f.y;
        }
        #pragma unroll
        for (int o = 32; o; o >>= 1) s += __shfl_down(s, o, 64);
        __shared__ float dred[NWAVE];
        if (lane == 0) dred[wave] = s;
        __syncthreads();
        if (tid == 0) {
            float t = 0.f;
            #pragma unroll
            for (int w = 0; w < NWAVE; ++w) t += dred[w];
            out[bid] = t + b_dec[bid];
        }
    }
}

extern "C" void kernel_launch(void* const* d_in, const int* in_sizes, int n_in,
                              void* d_out, int out_size, void* d_ws, size_t ws_size,
                              hipStream_t stream) {
    const int*   token  = (const int*)  d_in[0];
    const float* hidden = (const float*)d_in[1];
    const float* emb    = (const float*)d_in[2];
    const float* w_ih   = (const float*)d_in[3];
    const float* w_hh   = (const float*)d_in[4];
    const float* b_ih   = (const float*)d_in[5];
    const float* b_hh   = (const float*)d_in[6];
    const float* w_dec  = (const float*)d_in[7];
    const float* b_dec  = (const float*)d_in[8];

    float* out = (float*)d_out;
    char*  ws  = (char*)d_ws;

    // zero the barrier counters (graph replays reuse ws)
    (void)hipMemsetAsync(ws + WS_SUB_OFF, 0, WS_CTR_BYTES, stream);

    gru_fused<<<dim3(NBLK), dim3(NT), 0, stream>>>(
        token, hidden, emb, w_ih, w_hh, b_ih, b_hh,
        w_dec, b_dec, out, ws);
}